// Round 1
// baseline (188.832 us; speedup 1.0000x reference)
//
#include <hip/hip_runtime.h>

typedef unsigned short u16;
typedef __attribute__((ext_vector_type(4))) float f32x4;
typedef __attribute__((ext_vector_type(8))) short bf16x8;
typedef __attribute__((ext_vector_type(4))) u16 u16x4;
typedef __attribute__((ext_vector_type(8))) u16 u16x8;

__device__ __forceinline__ u16 f2bf(float f) {
    unsigned u = __float_as_uint(f);
    unsigned r = (u + 0x7FFFu + ((u >> 16) & 1u)) >> 16;
    return (u16)r;
}

__device__ __forceinline__ void gld16(const void* g, void* l) {
    __builtin_amdgcn_global_load_lds(
        (const __attribute__((address_space(1))) unsigned*)g,
        (__attribute__((address_space(3))) unsigned*)l,
        16, 0, 0);
}

// ---------------- cast fp32 -> bf16, vectorized ----------------
__global__ __launch_bounds__(256) void cast_kernel(const float* __restrict__ in,
                                                   u16* __restrict__ out, int n4) {
    int i = blockIdx.x * blockDim.x + threadIdx.x;
    int stride = gridDim.x * blockDim.x;
    for (; i < n4; i += stride) {
        f32x4 v = ((const f32x4*)in)[i];
        u16x4 o;
        o[0] = f2bf(v[0]); o[1] = f2bf(v[1]); o[2] = f2bf(v[2]); o[3] = f2bf(v[3]);
        ((u16x4*)out)[i] = o;
    }
}

// ---------------- bf16 GEMM: C = A[M,K] * B[N,K]^T ----------------
// 128x128 tile, 4 waves (2x2), 4x4 16x16 frags per wave, BK=64 as two 32-col
// sub-tiles. Linear LDS (global_load_lds constraint). m97-style structure.
// grid = (M/128, N/128, batches)
template <int OUT_F32>
__global__ __launch_bounds__(256, 2) void gemm_bt(
    const u16* __restrict__ A, const u16* __restrict__ Bm, void* __restrict__ C,
    int K, int ldc, long long sA, long long sB, long long sC, float scale) {
    A  += (long long)blockIdx.z * sA;
    Bm += (long long)blockIdx.z * sB;

    __shared__ __align__(16) u16 smem[16384];  // A: 16KB (2 x [128][32]), B: 16KB
    char* smc = (char*)smem;

    const int tid  = threadIdx.x;
    const int lane = tid & 63;
    const int wid  = tid >> 6;
    const int wr   = wid >> 1, wc = wid & 1;
    const int rowBase = blockIdx.x * 128;
    const int colBase = blockIdx.y * 128;

    f32x4 acc[4][4] = {};

    // byte offset of fragment base in LDS (sub-tile 0, frag 0)
    const int aBase = (wr * 64 + (lane & 15)) * 64 + (lane >> 4) * 16;
    const int bBase = 16384 + (wc * 64 + (lane & 15)) * 64 + (lane >> 4) * 16;

    for (int kt = 0; kt < K; kt += 64) {
#pragma unroll
        for (int i = 0; i < 4; i++) {  // A tile: 16KB = 4 x 4KB issues
            int off = i * 4096 + tid * 16;      // byte offset within A region
            int s   = off >> 13;                // sub-tile
            int r   = (off >> 6) & 127;         // row
            int k   = (s << 5) | ((off & 63) >> 1);
            const u16* g = A + (size_t)(rowBase + r) * K + (kt + k);
            gld16(g, smc + i * 4096 + ((tid >> 6) << 10));  // wave-uniform LDS base
        }
#pragma unroll
        for (int i = 0; i < 4; i++) {  // B tile
            int off = i * 4096 + tid * 16;
            int s   = off >> 13;
            int r   = (off >> 6) & 127;
            int k   = (s << 5) | ((off & 63) >> 1);
            const u16* g = Bm + (size_t)(colBase + r) * K + (kt + k);
            gld16(g, smc + 16384 + i * 4096 + ((tid >> 6) << 10));
        }
        __syncthreads();  // drains vmcnt before barrier -> staged data visible

#pragma unroll
        for (int s = 0; s < 2; s++) {
            bf16x8 af[4], bfr[4];
#pragma unroll
            for (int mi = 0; mi < 4; mi++)
                af[mi] = *(const bf16x8*)(smc + s * 8192 + aBase + mi * 1024);
#pragma unroll
            for (int nj = 0; nj < 4; nj++)
                bfr[nj] = *(const bf16x8*)(smc + s * 8192 + bBase + nj * 1024);
#pragma unroll
            for (int mi = 0; mi < 4; mi++)
#pragma unroll
                for (int nj = 0; nj < 4; nj++)
                    acc[mi][nj] = __builtin_amdgcn_mfma_f32_16x16x32_bf16(
                        af[mi], bfr[nj], acc[mi][nj], 0, 0, 0);
        }
        __syncthreads();  // all reads done before next stage overwrites
    }

    // epilogue: C/D layout col = lane&15, row = (lane>>4)*4 + j
    const int row0 = rowBase + wr * 64 + (lane >> 4) * 4;
    const int col0 = colBase + wc * 64 + (lane & 15);
    long long cb = (long long)blockIdx.z * sC;
#pragma unroll
    for (int mi = 0; mi < 4; mi++) {
#pragma unroll
        for (int nj = 0; nj < 4; nj++) {
            f32x4 v = acc[mi][nj];
#pragma unroll
            for (int j = 0; j < 4; j++) {
                size_t idx = (size_t)(row0 + mi * 16 + j) * ldc + (col0 + nj * 16);
                if (OUT_F32)
                    ((float*)C)[cb + idx] = v[j] * scale;
                else
                    ((u16*)C)[cb + idx] = f2bf(v[j] * scale);
            }
        }
    }
}

// ---------------- row softmax: fp32 scores [rows,2048] -> bf16 P ----------------
__global__ __launch_bounds__(256) void softmax_kernel(const float* __restrict__ S,
                                                      u16* __restrict__ P) {
    const int row  = blockIdx.x;
    const int tid  = threadIdx.x;
    const int lane = tid & 63;
    const int wid  = tid >> 6;
    const float* s = S + (size_t)row * 2048;

    f32x4 v0 = ((const f32x4*)s)[tid * 2];
    f32x4 v1 = ((const f32x4*)s)[tid * 2 + 1];

    float m = v0[0];
#pragma unroll
    for (int j = 1; j < 4; j++) m = fmaxf(m, v0[j]);
#pragma unroll
    for (int j = 0; j < 4; j++) m = fmaxf(m, v1[j]);
#pragma unroll
    for (int off = 32; off >= 1; off >>= 1) m = fmaxf(m, __shfl_xor(m, off));

    __shared__ float red[8];
    if (lane == 0) red[wid] = m;
    __syncthreads();
    m = fmaxf(fmaxf(red[0], red[1]), fmaxf(red[2], red[3]));

    float e[8];
    float sum = 0.f;
#pragma unroll
    for (int j = 0; j < 4; j++) { e[j] = __expf(v0[j] - m); sum += e[j]; }
#pragma unroll
    for (int j = 0; j < 4; j++) { e[4 + j] = __expf(v1[j] - m); sum += e[4 + j]; }
#pragma unroll
    for (int off = 32; off >= 1; off >>= 1) sum += __shfl_xor(sum, off);
    if (lane == 0) red[4 + wid] = sum;
    __syncthreads();
    sum = (red[4] + red[5]) + (red[6] + red[7]);

    float inv = 1.0f / sum;
    u16x8 o;
#pragma unroll
    for (int j = 0; j < 8; j++) o[j] = f2bf(e[j] * inv);
    ((u16x8*)(P + (size_t)row * 2048))[tid] = o;
}

// ---------------- launch ----------------
extern "C" void kernel_launch(void* const* d_in, const int* in_sizes, int n_in,
                              void* d_out, int out_size, void* d_ws, size_t ws_size,
                              hipStream_t stream) {
    const float* x  = (const float*)d_in[0];
    const float* Wk = (const float*)d_in[1];
    const float* Wq = (const float*)d_in[2];
    const float* Wv = (const float*)d_in[3];
    float* out = (float*)d_out;
    char* ws = (char*)d_ws;
    const size_t MB = 1u << 20;

    // region [0,64MB): xb+W casts first, then reused for fp32 scores
    u16* xb   = (u16*)(ws);             // 16MB: x as bf16 [B*S,1024]
    u16* Wkb  = (u16*)(ws + 16 * MB);   // 2MB
    u16* Wqb  = (u16*)(ws + 18 * MB);
    u16* Wvb  = (u16*)(ws + 20 * MB);
    float* sc = (float*)(ws);           // 64MB: scores [B][2048][2048] (xb/W dead)
    u16* Qb   = (u16*)(ws + 64 * MB);   // 16MB [B][2048][1024]
    u16* Kb   = (u16*)(ws + 80 * MB);   // 16MB
    u16* VTb  = (u16*)(ws + 96 * MB);   // 16MB: V^T [B][1024][2048]
    u16* Pb   = (u16*)(ws + 112 * MB);  // 32MB: softmax weights bf16 [B][2048][2048]

    const long long SB = 2048LL * 1024;  // per-batch x/Q/K/V elements

    cast_kernel<<<2048, 256, 0, stream>>>(x, xb, 8388608 / 4);
    cast_kernel<<<1024, 256, 0, stream>>>(Wk, Wkb, 1048576 / 4);
    cast_kernel<<<1024, 256, 0, stream>>>(Wq, Wqb, 1048576 / 4);
    cast_kernel<<<1024, 256, 0, stream>>>(Wv, Wvb, 1048576 / 4);

    // Q = x @ Wq^T : per batch M=2048,N=1024,K=1024
    gemm_bt<0><<<dim3(16, 8, 4), 256, 0, stream>>>(xb, Wqb, Qb, 1024, 1024, SB, 0, SB, 1.0f);
    // K = x @ Wk^T
    gemm_bt<0><<<dim3(16, 8, 4), 256, 0, stream>>>(xb, Wkb, Kb, 1024, 1024, SB, 0, SB, 1.0f);
    // V^T = Wv @ x^T : per batch M=1024,N=2048,K=1024 -> VT[o][s]
    gemm_bt<0><<<dim3(8, 16, 4), 256, 0, stream>>>(Wvb, xb, VTb, 1024, 2048, 0, SB, SB, 1.0f);
    // scores = (Q @ K^T) / 32 : M=N=2048,K=1024, fp32 out
    gemm_bt<1><<<dim3(16, 16, 4), 256, 0, stream>>>(Qb, Kb, sc, 1024, 2048, SB, SB,
                                                    2048LL * 2048, 0.03125f);
    // P = softmax(scores) rows, bf16
    softmax_kernel<<<8192, 256, 0, stream>>>(sc, Pb);
    // ctx = P @ VT^T : M=2048,N=1024,K=2048, fp32 out
    gemm_bt<1><<<dim3(16, 8, 4), 256, 0, stream>>>(Pb, VTb, out, 2048, 1024,
                                                   2048LL * 2048, SB, SB, 1.0f);
}